// Round 3
// baseline (125.995 us; speedup 1.0000x reference)
//
#include <hip/hip_runtime.h>
#include <hip/hip_bf16.h>

#define D 128
#define BS_STRIDE 136  // padded bf16 row stride: 272 B = 16B-aligned, 2-way bank alias (free)

typedef __attribute__((ext_vector_type(8))) short short8;
typedef __attribute__((ext_vector_type(4))) float float4_t;

// ---------------------------------------------------------------------------
// Kernel 1: fold the 4 candidate ops into one combined matrix/bias.
//   Wc[f][d] = sum_o weights[o] * W[o][f][d]   (stored bf16)
//   bc[f]    = sum_o weights[o] * b[o][f]      (stored fp32)
// ---------------------------------------------------------------------------
__global__ void combine_kernel(const float* __restrict__ W,
                               const float* __restrict__ b,
                               const float* __restrict__ wts,
                               __hip_bfloat16* __restrict__ Wc,
                               float* __restrict__ bc) {
    int idx = blockIdx.x * blockDim.x + threadIdx.x;
    float w0 = wts[0], w1 = wts[1], w2 = wts[2], w3 = wts[3];
    if (idx < D * D) {
        float v = w0 * W[idx] + w1 * W[D * D + idx]
                + w2 * W[2 * D * D + idx] + w3 * W[3 * D * D + idx];
        Wc[idx] = __float2bfloat16(v);
    }
    if (idx < D) {
        bc[idx] = w0 * b[idx] + w1 * b[D + idx] + w2 * b[2 * D + idx] + w3 * b[3 * D + idx];
    }
}

__device__ inline short8 cvt8_bf16(float4_t a, float4_t b) {
    union { short8 s; __hip_bfloat16 h[8]; } u;
    u.h[0] = __float2bfloat16(a[0]);
    u.h[1] = __float2bfloat16(a[1]);
    u.h[2] = __float2bfloat16(a[2]);
    u.h[3] = __float2bfloat16(a[3]);
    u.h[4] = __float2bfloat16(b[0]);
    u.h[5] = __float2bfloat16(b[1]);
    u.h[6] = __float2bfloat16(b[2]);
    u.h[7] = __float2bfloat16(b[3]);
    return u.s;
}

// ---------------------------------------------------------------------------
// Kernel 2: y[m][f] = sum_d x[m][d] * Wc[f][d] + bc[f]
// Grid = M/128 = 1024 blocks (4/CU, LDS-capped). 256 thr = 4 waves; each wave
// computes a 32-row x 128-col slab (two 16-row m-tiles sharing A-frags).
// Operands: A = Wc (LDS, i = f), B = x (global, j = m)  ==>  D-layout gives
// each lane 4 CONSECUTIVE f for one m -> float4 epilogue stores.
// ---------------------------------------------------------------------------
__global__ __launch_bounds__(256, 4) void gemm_kernel(const float* __restrict__ x,
                                                      const __hip_bfloat16* __restrict__ Wc,
                                                      const float* __restrict__ bc,
                                                      float* __restrict__ y,
                                                      int M) {
    __shared__ __align__(16) __hip_bfloat16 Bs[D * BS_STRIDE];  // 34816 B

    const int tid  = threadIdx.x;
    const int lane = tid & 63;
    const int wave = tid >> 6;

    // ---- stage Wc -> LDS (2048 chunks of 8 bf16; coalesced 16 B loads) ----
    #pragma unroll
    for (int i = 0; i < 8; i++) {
        int c  = i * 256 + tid;      // 0..2047
        int n  = c >> 4;             // Wc row f (0..127)
        int ko = (c & 15) << 3;      // k offset (0,8,...,120)
        short8 v = *(const short8*)((const short*)Wc + n * D + ko);
        *(short8*)((short*)Bs + n * BS_STRIDE + ko) = v;
    }
    __syncthreads();

    const int l15  = lane & 15;
    const int quad = lane >> 4;
    const int m_base = blockIdx.x * 128 + wave * 32;
    if (m_base >= M) return;

    float4_t acc[2][8];
    #pragma unroll
    for (int t = 0; t < 2; t++)
        #pragma unroll
        for (int nt = 0; nt < 8; nt++) acc[t][nt] = (float4_t)(0.f);

    // B-frag source rows: x[m_base + l15] and x[m_base + 16 + l15]
    const float* xr0 = x + (size_t)(m_base + l15) * D;
    const float* xr1 = xr0 + 16 * D;

    #pragma unroll
    for (int ks = 0; ks < 4; ks++) {
        const int koff = ks * 32 + quad * 8;   // B[k=quad*8+j][m=l15]
        short8 b0 = cvt8_bf16(*(const float4_t*)(xr0 + koff),
                              *(const float4_t*)(xr0 + koff + 4));
        short8 b1 = cvt8_bf16(*(const float4_t*)(xr1 + koff),
                              *(const float4_t*)(xr1 + koff + 4));
        const short* ap = (const short*)Bs + koff;
        #pragma unroll
        for (int nt = 0; nt < 8; nt++) {
            // A[i = f' = l15][k = quad*8+j] from LDS row nt*16 + l15
            short8 af = *(const short8*)(ap + (nt * 16 + l15) * BS_STRIDE);
            acc[0][nt] = __builtin_amdgcn_mfma_f32_16x16x32_bf16(af, b0, acc[0][nt], 0, 0, 0);
            acc[1][nt] = __builtin_amdgcn_mfma_f32_16x16x32_bf16(af, b1, acc[1][nt], 0, 0, 0);
        }
    }

    // ---- epilogue: lane holds m = m_base + t*16 + l15, f = nt*16 + quad*4 + r
    #pragma unroll
    for (int nt = 0; nt < 8; nt++) {
        float4_t bias = *(const float4_t*)(bc + nt * 16 + quad * 4);
        #pragma unroll
        for (int t = 0; t < 2; t++) {
            float4_t v = acc[t][nt] + bias;
            *(float4_t*)(y + (size_t)(m_base + t * 16 + l15) * D + nt * 16 + quad * 4) = v;
        }
    }
}

extern "C" void kernel_launch(void* const* d_in, const int* in_sizes, int n_in,
                              void* d_out, int out_size, void* d_ws, size_t ws_size,
                              hipStream_t stream) {
    const float* x   = (const float*)d_in[0];   // (B,S,D) fp32
    const float* W   = (const float*)d_in[1];   // (4,D,D) fp32
    const float* b   = (const float*)d_in[2];   // (4,D) fp32
    const float* wts = (const float*)d_in[3];   // (4,) fp32
    float* y = (float*)d_out;

    __hip_bfloat16* Wc = (__hip_bfloat16*)d_ws;
    float* bc = (float*)((char*)d_ws + D * D * sizeof(__hip_bfloat16));

    combine_kernel<<<(D * D + 255) / 256, 256, 0, stream>>>(W, b, wts, Wc, bc);

    const int M = in_sizes[0] / D;          // B*S = 131072
    gemm_kernel<<<M / 128, 256, 0, stream>>>(x, Wc, bc, y, M);
}